// Round 6
// baseline (255.375 us; speedup 1.0000x reference)
//
#include <hip/hip_runtime.h>
#include <hip/hip_bf16.h>

using bf16 = __hip_bfloat16;
typedef __attribute__((ext_vector_type(8))) short short8;    // 8 bf16 = 4 VGPRs (MFMA A/B frag)
typedef __attribute__((ext_vector_type(16))) float f32x16;   // 32x32 MFMA C/D frag

// ---------------------------------------------------------------------------
// All fp32->bf16 casts in ONE launch: blocks [0,8192) = x, [8192,11264) = W.
// ---------------------------------------------------------------------------
__global__ __launch_bounds__(256) void cast_all(const float* __restrict__ x,
                                                const float* __restrict__ Wq,
                                                const float* __restrict__ Wk,
                                                const float* __restrict__ Wv,
                                                bf16* __restrict__ xb, bf16* __restrict__ Wb) {
  const int b = blockIdx.x;
  const float* src;
  bf16* dst;
  if (b < 8192) {
    src = x + (size_t)b * 1024;
    dst = xb + (size_t)b * 1024;
  } else if (b < 9216) {
    src = Wq + (size_t)(b - 8192) * 1024;
    dst = Wb + (size_t)(b - 8192) * 1024;
  } else if (b < 10240) {
    src = Wk + (size_t)(b - 9216) * 1024;
    dst = Wb + (size_t)(b - 8192) * 1024;
  } else {
    src = Wv + (size_t)(b - 10240) * 1024;
    dst = Wb + (size_t)(b - 8192) * 1024;
  }
  const int i = threadIdx.x * 4;
  const float4 f = *(const float4*)(src + i);
  bf16 h[4];
  h[0] = __float2bfloat16(f.x);
  h[1] = __float2bfloat16(f.y);
  h[2] = __float2bfloat16(f.z);
  h[3] = __float2bfloat16(f.w);
  *(uint2*)(dst + i) = *(const uint2*)h;
}

// ---------------------------------------------------------------------------
// R14: 256x256 NT GEMM, faithful m201-style 4-phase/K-tile schedule.
// Geometry: 512 thr = 8 waves (wr = wave>>2 in {0,1}, wc = wave&3). Wave
// output = TWO 64-row granules rows {h*128 + wr*64 ..+64}, cols wc*64..+64.
// This granule mapping makes A-half h = block rows h*128..+128 CONTIGUOUS in
// LDS and read ONLY in phases {p0,p1} (h=0) / {p2,p3} (h=1) -> halves retire
// phase-by-phase, enabling mid-tile overwrite by the +2-tile staging stream.
// LDS: 2 buffers x (A 32K + B 32K) = 128 KiB. Each matrix stored as 2 k-planes
// [256 rows][64 B] (64 B rows + XOR chunk swizzle f(row)=(row+(row>>2))&3:
// proven ~0-conflict layout). Half-tile = 16 KB = 2 global_load_lds per wave.
// Per K-tile (4 phases, each: [ds_reads] ; stage 1 half ; barrier ; lgkm(0) ;
// setprio(1) 8xMFMA setprio(0) ; barrier):
//   p0: read A(h0) 8 + B(all) 8 ; stage A0(t+1)->other buf ; MFMA(h0,nt0)
//   p1:                           stage B0(t+2)->THIS buf  ; MFMA(h0,nt1)
//   p2: read A(h1) 8            ; stage B1(t+2)->THIS buf  ; MFMA(h1,nt0)
//   p3:                           stage A1(t+2)->THIS buf ; vmcnt(6) ; MFMA(h1,nt1)
// Overwrite safety: B last read p0, A1 last read p2; each stage of a half is
// issued only after the barrier that retires its last reader. vmcnt(6)
// (3 halves x 2 loads in flight) at p3 => tile t+1 fully landed (FIFO).
// vmcnt(0) only at kt==NT-2. Issue->wait distance ~4 phases.
// Half-tile stage stream for tile T: B0@(T-2,p1), B1@(T-2,p2), A1@(T-2,p3),
// A0@(T-1,p0); prologue = tile0 all + tile1 {B0,B1,A1}.
// MFMA 32x32x16 (verified mappings); acc[4][2] f32x16 = 128 VGPR.
// ---------------------------------------------------------------------------
#define MM_PHASE(H, NTQ)                                                        \
  _Pragma("unroll") for (int ks = 0; ks < 4; ++ks)                              \
    _Pragma("unroll") for (int mtq = 0; mtq < 2; ++mtq)                         \
      acc[(H)*2 + mtq][(NTQ)] = __builtin_amdgcn_mfma_f32_32x32x16_bf16(        \
          af[ks][mtq], bv[ks][(NTQ)], acc[(H)*2 + mtq][(NTQ)], 0, 0, 0);

template <class Epi>
__device__ __forceinline__ void gemm256(const bf16* __restrict__ A, const bf16* __restrict__ B,
                                        int lda, int ldb, int K, int m0, int n0, Epi epi) {
  __shared__ char smem[131072];
  const int t = threadIdx.x;   // 0..511
  const int lane = t & 63;
  const int wave = t >> 6;     // 0..7
  const int wr = wave >> 2;    // 0..1
  const int wc = wave & 3;     // 0..3
  const int rl = lane & 31;
  const int grp = lane >> 5;

  f32x16 acc[4][2];
#pragma unroll
  for (int i = 0; i < 4; ++i)
#pragma unroll
    for (int j = 0; j < 2; ++j)
#pragma unroll
      for (int r = 0; r < 16; ++r) acc[i][j][r] = 0.f;

  // Per-thread staging source base. Stage slot s = t: local row = t>>2 (half
  // adds +128 rows), chunk = (t&3) ^ f(row) (f invariant under +128).
  const int srow = t >> 2;
  const int sf = (srow + (srow >> 2)) & 3;
  const int sc = ((t & 3) ^ sf) << 3;  // element offset
  const bf16* baseA = A + (size_t)(m0 + srow) * lda + sc;
  const bf16* baseB = B + (size_t)(n0 + srow) * ldb + sc;

  // Stage one half-tile (mat 0=A,1=B; half h; K-tile kt) -> buf kt&1.
  auto stage = [&](int mat, int h, int kt) {
    const bf16* src = (mat ? baseB : baseA) + (size_t)h * 128 * (mat ? ldb : lda) + kt * 64;
    char* dst = smem + (kt & 1) * 65536 + mat * 32768 + h * 8192 + wave * 1024;
#pragma unroll
    for (int j = 0; j < 2; ++j)  // k-plane j
      __builtin_amdgcn_global_load_lds(
          (const __attribute__((address_space(1))) unsigned int*)(src + j * 32),
          (__attribute__((address_space(3))) unsigned int*)(dst + j * 16384), 16, 0, 0);
  };

  short8 af[4][2], bv[4][2];  // [ks][mtq] / [ks][nt]

  auto readA = [&](const char* bufA, int h) {
#pragma unroll
    for (int ks = 0; ks < 4; ++ks)
#pragma unroll
      for (int mtq = 0; mtq < 2; ++mtq) {
        const int row = h * 128 + wr * 64 + mtq * 32 + rl;
        const int fz = (row + (row >> 2)) & 3;
        const int kb = (ks & 1) * 2 + grp;
        af[ks][mtq] =
            *(const short8*)(bufA + (ks >> 1) * 16384 + row * 64 + ((kb ^ fz) << 4));
      }
  };
  auto readB = [&](const char* bufB) {
#pragma unroll
    for (int ks = 0; ks < 4; ++ks)
#pragma unroll
      for (int nt = 0; nt < 2; ++nt) {
        const int row = wc * 64 + nt * 32 + rl;
        const int fz = (row + (row >> 2)) & 3;
        const int kb = (ks & 1) * 2 + grp;
        bv[ks][nt] =
            *(const short8*)(bufB + (ks >> 1) * 16384 + row * 64 + ((kb ^ fz) << 4));
      }
  };

  const int NT = K >> 6;  // K-tiles of 64; >= 16 at all call sites

  // Prologue: tile0 {A0,A1,B0,B1} (8 loads) + tile1 {B0,B1,A1} (6 loads).
  stage(0, 0, 0); stage(0, 1, 0); stage(1, 0, 0); stage(1, 1, 0);
  stage(1, 0, 1); stage(1, 1, 1); stage(0, 1, 1);
  asm volatile("s_waitcnt vmcnt(6)" ::: "memory");  // tile0 landed; tile1's 6 fly
  __builtin_amdgcn_s_barrier();
  __builtin_amdgcn_sched_barrier(0);

  for (int kt = 0; kt < NT; ++kt) {
    const char* bufA = smem + (kt & 1) * 65536;
    const char* bufB = bufA + 32768;
    // ---- phase 0 ----
    readA(bufA, 0);
    readB(bufB);
    if (kt + 1 < NT) stage(0, 0, kt + 1);
    __builtin_amdgcn_s_barrier();
    asm volatile("s_waitcnt lgkmcnt(0)" ::: "memory");
    __builtin_amdgcn_sched_barrier(0);
    __builtin_amdgcn_s_setprio(1);
    MM_PHASE(0, 0)
    __builtin_amdgcn_s_setprio(0);
    __builtin_amdgcn_s_barrier();
    // ---- phase 1 ----
    if (kt + 2 < NT) stage(1, 0, kt + 2);
    __builtin_amdgcn_s_barrier();
    __builtin_amdgcn_s_setprio(1);
    MM_PHASE(0, 1)
    __builtin_amdgcn_s_setprio(0);
    __builtin_amdgcn_s_barrier();
    // ---- phase 2 ----
    readA(bufA, 1);
    if (kt + 2 < NT) stage(1, 1, kt + 2);
    __builtin_amdgcn_s_barrier();
    asm volatile("s_waitcnt lgkmcnt(0)" ::: "memory");
    __builtin_amdgcn_sched_barrier(0);
    __builtin_amdgcn_s_setprio(1);
    MM_PHASE(1, 0)
    __builtin_amdgcn_s_setprio(0);
    __builtin_amdgcn_s_barrier();
    // ---- phase 3 ----
    if (kt + 2 < NT) {
      stage(0, 1, kt + 2);
      asm volatile("s_waitcnt vmcnt(6)" ::: "memory");  // tile kt+1 fully landed
    } else if (kt + 1 < NT) {
      asm volatile("s_waitcnt vmcnt(0)" ::: "memory");  // tail drain (kt==NT-2)
    }
    __builtin_amdgcn_s_barrier();
    __builtin_amdgcn_s_setprio(1);
    MM_PHASE(1, 1)
    __builtin_amdgcn_s_setprio(0);
    __builtin_amdgcn_s_barrier();
  }
  __syncthreads();  // full drain before epilogue smem reuse

  epi(acc, m0, n0, wr, wc, lane, wave, (char*)smem);
}

// C/D row offset within a 32x32 tile for (reg, lane): m74/m101-verified.
__device__ __forceinline__ int c_row(int reg, int lane) {
  return (reg & 3) + 8 * (reg >> 2) + 4 * (lane >> 5);
}

// Row/col enumeration for the granule wave tile (rows h*128 + wr*64 + mtq*32).
template <class F>
__device__ __forceinline__ void for_each_c(const f32x16 (&acc)[4][2], int wr, int wc, int lane,
                                           F f) {
  const int rl = lane & 31;
#pragma unroll
  for (int h = 0; h < 2; ++h)
#pragma unroll
    for (int mtq = 0; mtq < 2; ++mtq)
#pragma unroll
      for (int nt = 0; nt < 2; ++nt)
#pragma unroll
        for (int reg = 0; reg < 16; ++reg)
          f(h * 128 + wr * 64 + mtq * 32 + c_row(reg, lane), wc * 64 + nt * 32 + rl,
            acc[h * 2 + mtq][nt][reg]);
}

// ---------------------------------------------------------------------------
// Projection: C[8192, 3072] = xb[8192,1024] @ Wb[3072,1024]^T. Grid 384.
// XCD swizzle: XCD g owns m-quad (g*4 + 0..3) x all 12 n -> A 2 MB resident.
// n0<1024 -> Q; n0<2048 -> K; else V^T via per-wave LDS transpose.
// ---------------------------------------------------------------------------
__global__ __launch_bounds__(512, 2) void proj_kernel(const bf16* __restrict__ xb,
                                                      const bf16* __restrict__ Wb,
                                                      bf16* __restrict__ Qb,
                                                      bf16* __restrict__ Kb,
                                                      bf16* __restrict__ Vt) {
  const int id = blockIdx.x;             // [0,384)
  const int g = id & 7, s = id >> 3;     // s in [0,48)
  const int m0 = (g * 4 + (s & 3)) * 256;  // 32 m-tiles
  const int n0 = (s >> 2) * 256;           // 12 n-tiles
  gemm256(xb, Wb, 1024, 1024, 1024, m0, n0,
          [=](const f32x16 (&acc)[4][2], int m0, int n0, int wr, int wc, int lane, int wave,
              char* smem) {
    if (n0 < 2048) {  // block-uniform branch
      bf16* dst = (n0 < 1024) ? Qb : Kb;
      const int nb = n0 & 1023;
      for_each_c(acc, wr, wc, lane, [&](int m, int n, float v) {
        dst[(size_t)(m0 + m) * 1024 + nb + n] = __float2bfloat16(v);
      });
    } else {
      // V tile: per-wave transpose through LDS; 4 passes of (64 m x 32 n).
      bf16* T = (bf16*)smem + wave * 2304;  // 32 n-rows x stride 72 = 4608 B/wave
      const int rl = lane & 31;
      const int g4 = 4 * (lane >> 5);
      const int nvb = n0 - 2048 + wc * 64;
#pragma unroll
      for (int h = 0; h < 2; ++h) {
        const int mbase = m0 + h * 128 + wr * 64;
        const int bb = mbase >> 11;
        const int sbase = mbase & 2047;
#pragma unroll
        for (int p = 0; p < 2; ++p) {  // nt half
#pragma unroll
          for (int mtq = 0; mtq < 2; ++mtq)
#pragma unroll
            for (int q = 0; q < 4; ++q) {
              bf16 h4[4];
#pragma unroll
              for (int r = 0; r < 4; ++r)
                h4[r] = __float2bfloat16(acc[h * 2 + mtq][p][4 * q + r]);
              *(uint2*)(T + rl * 72 + mtq * 32 + 8 * q + g4) = *(const uint2*)h4;
            }
          asm volatile("s_waitcnt lgkmcnt(0)" ::: "memory");  // wave-local LDS RAW
#pragma unroll
          for (int i = 0; i < 4; ++i) {
            const int nl = i * 8 + (lane >> 3);
            const int ml = (lane & 7) * 8;
            const short8 val = *(const short8*)(T + nl * 72 + ml);
            *(short8*)(Vt + ((size_t)bb * 1024 + nvb + p * 32 + nl) * 2048 + sbase + ml) = val;
          }
          asm volatile("s_waitcnt lgkmcnt(0)" ::: "memory");  // reads retired before reuse
        }
      }
    }
  });
}

// ---------------------------------------------------------------------------
// QK^T + fused exp: E[z][m][n] = exp(Q.K/32) bf16 + per-256-col-tile partial
// row sums Lpart[z][8][2048]. No max-subtract (s ~ N(0,1); exp safe in fp32).
// Grid (64,4) = 256 blocks = 1/CU. Per z, XCD g owns a 2m x 4n patch.
// ---------------------------------------------------------------------------
__global__ __launch_bounds__(512, 2) void qk_exp_kernel(const bf16* __restrict__ Qb,
                                                        const bf16* __restrict__ Kb,
                                                        bf16* __restrict__ E,
                                                        float* __restrict__ Lpart) {
  const int z = blockIdx.y;
  const int id2 = blockIdx.x;              // [0,64)
  const int g = id2 & 7, s = id2 >> 3;     // s in [0,8)
  const int m0 = ((g & 3) * 2 + (s & 1)) * 256;   // 8 m-tiles
  const int n0 = ((g >> 2) * 4 + (s >> 1)) * 256; // 8 n-tiles
  const bf16* A = Qb + (size_t)z * 2048 * 1024;
  const bf16* B = Kb + (size_t)z * 2048 * 1024;
  bf16* Ez = E + (size_t)z * 2048 * 2048;
  float* Lz = Lpart + (size_t)z * 8 * 2048;
  gemm256(A, B, 1024, 1024, 1024, m0, n0,
          [=](const f32x16 (&acc)[4][2], int m0, int n0, int wr, int wc, int lane, int wave,
              char* smem) {
    float* Lp = (float*)smem;  // [256][4] per-wave-column partials
    const int rl = lane & 31;
#pragma unroll
    for (int h = 0; h < 2; ++h)
#pragma unroll
      for (int mtq = 0; mtq < 2; ++mtq)
#pragma unroll
        for (int reg = 0; reg < 16; ++reg) {
          const int mr = h * 128 + wr * 64 + mtq * 32 + c_row(reg, lane);
          float s2 = 0.f;
#pragma unroll
          for (int nt = 0; nt < 2; ++nt) {
            const float e = __expf(acc[h * 2 + mtq][nt][reg] * 0.03125f);
            Ez[(size_t)(m0 + mr) * 2048 + n0 + wc * 64 + nt * 32 + rl] = __float2bfloat16(e);
            s2 += e;
          }
          s2 += __shfl_xor(s2, 1, 64);
          s2 += __shfl_xor(s2, 2, 64);
          s2 += __shfl_xor(s2, 4, 64);
          s2 += __shfl_xor(s2, 8, 64);
          s2 += __shfl_xor(s2, 16, 64);
          if (rl == 0) Lp[mr * 4 + wc] = s2;
        }
    __syncthreads();
    const int t = threadIdx.x;
    if (t < 256)
      Lz[(n0 >> 8) * 2048 + m0 + t] =
          Lp[t * 4 + 0] + Lp[t * 4 + 1] + Lp[t * 4 + 2] + Lp[t * 4 + 3];
  });
}

// ---------------------------------------------------------------------------
// out[z][q][d] = invL[z][q] * sum_k E[z][q,k] * Vt[z][d,k].  K = 2048.
// Grid (32,4) = 128 blocks (half-chip — accepted this round). invL from Lpart.
// ---------------------------------------------------------------------------
__global__ __launch_bounds__(512, 2) void pv_kernel(const bf16* __restrict__ E,
                                                    const bf16* __restrict__ Vt,
                                                    const float* __restrict__ Lpart,
                                                    float* __restrict__ out) {
  const int z = blockIdx.y;
  const int id2 = blockIdx.x;              // [0,32)
  const int g = id2 & 7, s = id2 >> 3;     // s in [0,4)
  const int m0 = ((g & 3) * 2 + (s & 1)) * 256;   // 8 m-tiles
  const int n0 = ((g >> 2) * 2 + (s >> 1)) * 256; // 4 n-tiles
  const bf16* A = E + (size_t)z * 2048 * 2048;
  const bf16* B = Vt + (size_t)z * 1024 * 2048;
  const float* Lz = Lpart + (size_t)z * 8 * 2048;
  float* oz = out + (size_t)z * 2048 * 1024;
  gemm256(A, B, 2048, 2048, 2048, m0, n0,
          [=](const f32x16 (&acc)[4][2], int m0, int n0, int wr, int wc, int lane, int wave,
              char* smem) {
    float* Lsm = (float*)smem;  // invL for this block's 256 rows
    const int t = threadIdx.x;
    if (t < 256) {
      float s2 = 0.f;
#pragma unroll
      for (int i = 0; i < 8; ++i) s2 += Lz[(size_t)i * 2048 + m0 + t];
      Lsm[t] = 1.f / s2;
    }
    __syncthreads();
    const int rl = lane & 31;
#pragma unroll
    for (int h = 0; h < 2; ++h)
#pragma unroll
      for (int mtq = 0; mtq < 2; ++mtq)
#pragma unroll
        for (int reg = 0; reg < 16; ++reg) {
          const int ml = h * 128 + wr * 64 + mtq * 32 + c_row(reg, lane);
          const float il = Lsm[ml];
#pragma unroll
          for (int nt = 0; nt < 2; ++nt)
            oz[(size_t)(m0 + ml) * 1024 + n0 + wc * 64 + nt * 32 + rl] =
                acc[h * 2 + mtq][nt][reg] * il;
        }
  });
}

// ---------------------------------------------------------------------------
extern "C" void kernel_launch(void* const* d_in, const int* in_sizes, int n_in,
                              void* d_out, int out_size, void* d_ws, size_t ws_size,
                              hipStream_t stream) {
  const float* x = (const float*)d_in[0];
  const float* Wq = (const float*)d_in[1];
  const float* Wk = (const float*)d_in[2];
  const float* Wv = (const float*)d_in[3];
  float* out = (float*)d_out;

  // Workspace layout (~102 MB)
  char* w = (char*)d_ws;
  bf16* xb = (bf16*)w; w += (size_t)8192 * 1024 * 2;
  bf16* Wb = (bf16*)w; w += (size_t)3072 * 1024 * 2;
  bf16* Qb = (bf16*)w; w += (size_t)8192 * 1024 * 2;
  bf16* Kb = (bf16*)w; w += (size_t)8192 * 1024 * 2;
  bf16* Vt = (bf16*)w; w += (size_t)8192 * 1024 * 2;
  bf16* E  = (bf16*)w; w += (size_t)4 * 2048 * 2048 * 2;
  float* Lpart = (float*)w; w += (size_t)4 * 8 * 2048 * 4;

  // All casts in one launch
  cast_all<<<11264, 256, 0, stream>>>(x, Wq, Wk, Wv, xb, Wb);

  // Fused QKV projection (Q,K row-major bf16; V transposed bf16)
  proj_kernel<<<384, 512, 0, stream>>>(xb, Wb, Qb, Kb, Vt);

  // Scores -> exp (no max-subtract) + partial row sums per 256-col tile
  qk_exp_kernel<<<dim3(64, 4), 512, 0, stream>>>(Qb, Kb, E, Lpart);

  // Attention output with fused 1/L normalization
  pv_kernel<<<dim3(32, 4), 512, 0, stream>>>(E, Vt, Lpart, out);
}